// Round 5
// baseline (8255.083 us; speedup 1.0000x reference)
//
#include <hip/hip_runtime.h>
#include <cstdint>
#include <cstddef>

#define T_LEN 512
#define S_LEN 512
#define HID   1024
#define AD    256
#define VOC   50257
#define G3    3072
#define NWG   256
#define NT    512
#define NPART (197*4)

typedef unsigned long long u64;

// ---------------- workspace layout (float offsets) ----------------
#define WS_GENC   0
#define WS_GITOK  (WS_GENC + G3*S_LEN)          // [512][3072]
#define WS_EX     (WS_GITOK + T_LEN*G3)         // [512][256]
#define WS_H1     (WS_EX + S_LEN*AD)            // [512][1024]
#define WS_FC1    (WS_H1 + T_LEN*HID)           // [512][32]
#define WS_ROWP   (WS_FC1 + T_LEN*32)           // [512][788]
#define WS_INV    (WS_ROWP + T_LEN*NPART)
#define WS_TAGF   (((WS_INV + T_LEN) + 3) & ~3) // 16B-aligned start of tag region

// ---- tagged-dataflow region (u64 indices, dense) ----
#define TG_NH0 0                                 // 2*1024
#define TG_NH1 (TG_NH0 + 2*1024)                 // 2*1024
#define TG_W   (TG_NH1 + 2*1024)                 // 2*512
#define TG_U0  (TG_W   + 2*512)                  // 2*256
#define TG_U1  (TG_U0  + 2*256)
#define TG_E0  (TG_U1  + 2*256)
#define TG_E1  (TG_E0  + 2*256)
#define TG_TOT (TG_E1  + 2*256)                  // 7168 u64

__device__ inline float wred64(float v) {
  v += __shfl_xor(v, 32, 64); v += __shfl_xor(v, 16, 64); v += __shfl_xor(v, 8, 64);
  v += __shfl_xor(v, 4, 64);  v += __shfl_xor(v, 2, 64);  v += __shfl_xor(v, 1, 64);
  return v;
}
__device__ inline float fast_sigmoid(float x) { return 1.f / (1.f + __expf(-x)); }
__device__ inline float fast_tanh(float x) {
  float e = __expf(2.f * x);
  return 1.f - 2.f / (e + 1.f);
}

// ---- tagged 8B dataflow words: value+signal in one atomic ----
__device__ inline u64 ald(const u64* p) {
  return __hip_atomic_load(p, __ATOMIC_RELAXED, __HIP_MEMORY_SCOPE_AGENT);
}
__device__ inline void stq(u64* p, float v, unsigned tag) {
  __hip_atomic_store(p, ((u64)tag << 32) | (u64)__float_as_uint(v),
                     __ATOMIC_RELAXED, __HIP_MEMORY_SCOPE_AGENT);
}
// per-word early-exit polls: once a word's tag matches, never re-load it
__device__ inline float pollw(const u64* p, unsigned tag) {
  u64 x = ald(p);
  while ((unsigned)(x >> 32) != tag) { __builtin_amdgcn_s_sleep(2); x = ald(p); }
  return __uint_as_float((unsigned)x);
}
__device__ inline void poll2e(const u64* p0, const u64* p1, unsigned tag, float& r0, float& r1) {
  u64 x0 = ald(p0), x1 = ald(p1);
  while (true) {
    const bool d0 = ((unsigned)(x0 >> 32) == tag);
    const bool d1 = ((unsigned)(x1 >> 32) == tag);
    if (d0 & d1) break;
    __builtin_amdgcn_s_sleep(2);
    if (!d0) x0 = ald(p0);
    if (!d1) x1 = ald(p1);
  }
  r0 = __uint_as_float((unsigned)x0); r1 = __uint_as_float((unsigned)x1);
}
__device__ inline void poll3e(const u64* p0, const u64* p1, const u64* p2, unsigned tag,
                              float& r0, float& r1, float& r2) {
  u64 x0 = ald(p0), x1 = ald(p1), x2 = ald(p2);
  while (true) {
    const bool d0 = ((unsigned)(x0 >> 32) == tag);
    const bool d1 = ((unsigned)(x1 >> 32) == tag);
    const bool d2 = ((unsigned)(x2 >> 32) == tag);
    if (d0 & d1 & d2) break;
    __builtin_amdgcn_s_sleep(2);
    if (!d0) x0 = ald(p0);
    if (!d1) x1 = ald(p1);
    if (!d2) x2 = ald(p2);
  }
  r0 = __uint_as_float((unsigned)x0); r1 = __uint_as_float((unsigned)x1);
  r2 = __uint_as_float((unsigned)x2);
}

__device__ inline float qdot4(const float4& a0, const float4& a1, const float4& a2, const float4& a3,
                              const float4& x0, const float4& x1, const float4& x2, const float4& x3) {
  float a = 0.f;
  a = fmaf(a0.x, x0.x, a); a = fmaf(a0.y, x0.y, a); a = fmaf(a0.z, x0.z, a); a = fmaf(a0.w, x0.w, a);
  a = fmaf(a1.x, x1.x, a); a = fmaf(a1.y, x1.y, a); a = fmaf(a1.z, x1.z, a); a = fmaf(a1.w, x1.w, a);
  a = fmaf(a2.x, x2.x, a); a = fmaf(a2.y, x2.y, a); a = fmaf(a2.z, x2.z, a); a = fmaf(a2.w, x2.w, a);
  a = fmaf(a3.x, x3.x, a); a = fmaf(a3.y, x3.y, a); a = fmaf(a3.z, x3.z, a); a = fmaf(a3.w, x3.w, a);
  return a;
}
__device__ inline float qdot2(const float4& a0, const float4& a1,
                              const float4& x0, const float4& x1) {
  float a = 0.f;
  a = fmaf(a0.x, x0.x, a); a = fmaf(a0.y, x0.y, a); a = fmaf(a0.z, x0.z, a); a = fmaf(a0.w, x0.w, a);
  a = fmaf(a1.x, x1.x, a); a = fmaf(a1.y, x1.y, a); a = fmaf(a1.z, x1.z, a); a = fmaf(a1.w, x1.w, a);
  return a;
}

// ---------------- init: zero all tag words (tag 0 == initial zero state) ----------------
__global__ void k_init(float* ws) {
  u64* TG = (u64*)(ws + WS_TAGF);
  const int i = blockIdx.x * 256 + threadIdx.x;
  if (i < TG_TOT) TG[i] = 0ull;
}

// ---------------- generic tiled fp32 GEMM (pre/post passes) ----------------
__global__ __launch_bounds__(256) void k_gemm(
    const float* __restrict__ A, int lda, const int* __restrict__ gidx,
    const float* __restrict__ B, int ldb, int kofs,
    const float* __restrict__ bias, float* __restrict__ C, int ldc,
    int M, int N, int act)
{
  __shared__ float As[64][33];
  __shared__ float Bs[64][33];
  const int bm = blockIdx.y * 64, bn = blockIdx.x * 64;
  const int tx = threadIdx.x & 15, ty = threadIdx.x >> 4;
  float acc[4][4] = {};
  const int lin = threadIdx.x * 8;
  const int lr = lin >> 5;
  const int lc = lin & 31;
  for (int k0 = 0; k0 < 1024; k0 += 32) {
    {
      const int gm = bm + lr;
      float4 v0 = {0,0,0,0}, v1 = {0,0,0,0};
      if (gm < M) {
        const int row = gidx ? gidx[gm] : gm;
        const float* p = A + (size_t)row * lda + k0 + lc;
        v0 = *(const float4*)p; v1 = *(const float4*)(p + 4);
      }
      As[lr][lc+0]=v0.x; As[lr][lc+1]=v0.y; As[lr][lc+2]=v0.z; As[lr][lc+3]=v0.w;
      As[lr][lc+4]=v1.x; As[lr][lc+5]=v1.y; As[lr][lc+6]=v1.z; As[lr][lc+7]=v1.w;
    }
    {
      const int gn = bn + lr;
      float4 v0 = {0,0,0,0}, v1 = {0,0,0,0};
      if (gn < N) {
        const float* p = B + (size_t)gn * ldb + kofs + k0 + lc;
        v0 = *(const float4*)p; v1 = *(const float4*)(p + 4);
      }
      Bs[lr][lc+0]=v0.x; Bs[lr][lc+1]=v0.y; Bs[lr][lc+2]=v0.z; Bs[lr][lc+3]=v0.w;
      Bs[lr][lc+4]=v1.x; Bs[lr][lc+5]=v1.y; Bs[lr][lc+6]=v1.z; Bs[lr][lc+7]=v1.w;
    }
    __syncthreads();
    #pragma unroll
    for (int kk = 0; kk < 32; ++kk) {
      float a0 = As[ty*4+0][kk], a1 = As[ty*4+1][kk], a2 = As[ty*4+2][kk], a3 = As[ty*4+3][kk];
      float b0 = Bs[tx*4+0][kk], b1 = Bs[tx*4+1][kk], b2 = Bs[tx*4+2][kk], b3 = Bs[tx*4+3][kk];
      acc[0][0]=fmaf(a0,b0,acc[0][0]); acc[0][1]=fmaf(a0,b1,acc[0][1]); acc[0][2]=fmaf(a0,b2,acc[0][2]); acc[0][3]=fmaf(a0,b3,acc[0][3]);
      acc[1][0]=fmaf(a1,b0,acc[1][0]); acc[1][1]=fmaf(a1,b1,acc[1][1]); acc[1][2]=fmaf(a1,b2,acc[1][2]); acc[1][3]=fmaf(a1,b3,acc[1][3]);
      acc[2][0]=fmaf(a2,b0,acc[2][0]); acc[2][1]=fmaf(a2,b1,acc[2][1]); acc[2][2]=fmaf(a2,b2,acc[2][2]); acc[2][3]=fmaf(a2,b3,acc[2][3]);
      acc[3][0]=fmaf(a3,b0,acc[3][0]); acc[3][1]=fmaf(a3,b1,acc[3][1]); acc[3][2]=fmaf(a3,b2,acc[3][2]); acc[3][3]=fmaf(a3,b3,acc[3][3]);
    }
    __syncthreads();
  }
  #pragma unroll
  for (int i = 0; i < 4; ++i)
    #pragma unroll
    for (int j = 0; j < 4; ++j) {
      const int m = bm + ty*4 + i, n = bn + tx*4 + j;
      if (m < M && n < N) {
        float v = acc[i][j] + (bias ? bias[n] : 0.f);
        if (act == 1) v = fmaxf(v, 0.f);
        C[(size_t)m * ldc + n] = v;
      }
    }
}

// ---------------- persistent recurrence: 256 WGs x 512 thr, tagged dataflow ----------------
// Wave wv in {0..3} owns output column j = 4*wg + wv end-to-end:
//   holds gate-rows {j, 1024+j, 2048+j} of Whh0 / Wih1 / Whh1 / Genc in VGPRs and
//   keeps gh0 (per step), gh1 (persistent), nh1_old (persistent) in registers.
// Waves 4,5: attention-w rows s = 2wg, 2wg+1 (Ex+va in regs).
// Wave 6: Wh row wg (e0/e1 partials). Wave 7: Wac row wg (u0/u1).
__global__ __launch_bounds__(NT) void k_recur(
    float* __restrict__ ws,
    const float* __restrict__ Whh0, const float* __restrict__ bhh0,
    const float* __restrict__ Wih1, const float* __restrict__ bih1,
    const float* __restrict__ Whh1, const float* __restrict__ bhh1,
    const float* __restrict__ Wh,   const float* __restrict__ bh,
    const float* __restrict__ vh,   const float* __restrict__ vhb,
    const float* __restrict__ va,   const float* __restrict__ vab,
    const float* __restrict__ Wac)
{
  const float* Genc  = ws + WS_GENC;
  const float* gitok = ws + WS_GITOK;
  const float* Ex    = ws + WS_EX;
  float* H1 = ws + WS_H1;
  u64* TG   = (u64*)(ws + WS_TAGF);
  u64* tNH0 = TG + TG_NH0;
  u64* tNH1 = TG + TG_NH1;
  u64* tW   = TG + TG_W;
  u64* tU0  = TG + TG_U0;
  u64* tU1  = TG + TG_U1;
  u64* tE0  = TG + TG_E0;
  u64* tE1  = TG + TG_E1;

  const int wg = blockIdx.x, tid = threadIdx.x;
  const int lane = tid & 63, wv = tid >> 6;
  const int j = wg * 4 + wv;   // valid when wv < 4

  __shared__ float xva[HID];   // nh0 copy (and h0n during S1/S2)
  __shared__ float xvb[HID];   // nh1 copy
  __shared__ float wl[S_LEN];
  __shared__ float cb[AD];
  __shared__ float sred[8];

  // ---- persistent register-resident weights ----
  float4 wreg[42];
  if (wv < 4) {
    #pragma unroll
    for (int r3 = 0; r3 < 3; ++r3) {
      const int g = r3 * HID + j;
      const float4* p0 = (const float4*)(Whh0 + (size_t)g * HID);
      const float4* p1 = (const float4*)(Wih1 + (size_t)g * HID);
      const float4* p2 = (const float4*)(Whh1 + (size_t)g * HID);
      const float4* pg = (const float4*)(Genc + (size_t)g * S_LEN);
      #pragma unroll
      for (int p = 0; p < 4; ++p) {
        wreg[r3*4 + p]      = p0[p*64 + lane];
        wreg[12 + r3*4 + p] = p1[p*64 + lane];
        wreg[24 + r3*4 + p] = p2[p*64 + lane];
      }
      wreg[36 + r3*2]     = pg[lane];
      wreg[36 + r3*2 + 1] = pg[64 + lane];
    }
  } else if (wv < 6) {
    const int s = 2 * wg + (wv - 4);
    wreg[0] = ((const float4*)(Ex + (size_t)s * AD))[lane];
    wreg[1] = ((const float4*)va)[lane];
  } else {
    const float* Wrow = (wv == 6) ? (Wh + (size_t)wg * HID) : (Wac + (size_t)wg * HID);
    #pragma unroll
    for (int p = 0; p < 4; ++p) wreg[p] = ((const float4*)Wrow)[p*64 + lane];
  }

  // per-column biases / persistent state (uniform across the wave's lanes)
  float b0r=0,b0z=0,b0n=0, c1r=0,c1z=0,c1n=0, bh1r=0,bh1z=0,bh1n=0;
  float gh1r=0, gh1z=0, gh1n=0, oldn=0.f;
  if (wv < 4) {
    b0r = bhh0[j];  b0z = bhh0[HID+j];  b0n = bhh0[2*HID+j];
    c1r = bih1[j];  c1z = bih1[HID+j];  c1n = bih1[2*HID+j];
    bh1r = bhh1[j]; bh1z = bhh1[HID+j]; bh1n = bhh1[2*HID+j];
    gh1r = bh1r; gh1z = bh1z; gh1n = bh1n;   // gh1(t=0) = Whh1@0 + bhh1
  }
  const float vhW = vh[wg], bhW = bh[wg];
  const float vabv = vab[0], vhb0 = vhb[0];

  // zero LDS state copies (== zero initial hidden vectors)
  xva[tid] = 0.f; xva[tid+512] = 0.f;
  xvb[tid] = 0.f; xvb[tid+512] = 0.f;
  __syncthreads();

  float gh0r = 0.f, gh0z = 0.f, gh0n = 0.f;
  const float4* XA4 = (const float4*)xva;
  const float4* XB4 = (const float4*)xvb;
  const float4* WL4 = (const float4*)wl;

  #pragma unroll 1
  for (int t = 0; t < T_LEN; ++t) {
    const int c = t & 1, pc = c ^ 1;
    const unsigned tg = (unsigned)(t + 1);
    const unsigned tp = (unsigned)t;

    // ===== S1: alpha; h0n (local from xva/xvb); c; gh0 (regs); publish w =====
    {
      float ep, uu0 = 0.f, uu1 = 0.f;
      if (tid < 256) {
        poll3e(tE0 + pc*256 + tid, tU0 + pc*256 + tid, tU1 + pc*256 + tid, tp, ep, uu0, uu1);
      } else {
        ep = pollw(tE1 + pc*256 + (tid - 256), tp);
      }
      float eps = wred64(ep);
      if (lane == 0) sred[wv] = eps;
      __syncthreads();
      const float e0s = sred[0]+sred[1]+sred[2]+sred[3] + vhb0;
      const float e1s = sred[4]+sred[5]+sred[6]+sred[7] + vhb0;
      const float ea = __expf(e0s), eb = __expf(e1s);
      const float rs = 1.f / (ea + eb);
      const float al0 = ea * rs, al1 = eb * rs;
      const float h0 = al0 * xva[tid]       + al1 * xvb[tid];
      const float h1 = al0 * xva[tid + 512] + al1 * xvb[tid + 512];
      xva[tid] = h0; xva[tid + 512] = h1;          // xva := h0n
      if (tid < 256) cb[tid] = al0 * uu0 + al1 * uu1;
      __syncthreads();
      if (wv < 4) {
        const float4 x0 = XA4[lane], x1 = XA4[64+lane], x2 = XA4[128+lane], x3 = XA4[192+lane];
        gh0r = wred64(qdot4(wreg[0], wreg[1], wreg[2],  wreg[3],  x0,x1,x2,x3)) + b0r;
        gh0z = wred64(qdot4(wreg[4], wreg[5], wreg[6],  wreg[7],  x0,x1,x2,x3)) + b0z;
        gh0n = wred64(qdot4(wreg[8], wreg[9], wreg[10], wreg[11], x0,x1,x2,x3)) + b0n;
      } else if (wv < 6) {
        const float4 e4 = wreg[0], v4 = wreg[1];
        const float4 c4 = ((const float4*)cb)[lane];
        float acc = v4.x * fast_tanh(e4.x + c4.x) + v4.y * fast_tanh(e4.y + c4.y)
                  + v4.z * fast_tanh(e4.z + c4.z) + v4.w * fast_tanh(e4.w + c4.w);
        acc = wred64(acc);
        if (lane == 0) stq(tW + c*512 + 2*wg + (wv - 4), __expf(acc + vabv), tg);
      }
    }

    // ===== S2: gather w; nh0 = GRU0((Genc@w)/sum + gitok, gh0, h0n); publish nh0 =====
    {
      float g0 = 0.f, g1 = 0.f, g2 = 0.f;
      if (wv < 4) {   // prefetch (cached) before the poll
        const float* gp = gitok + (size_t)t * G3 + j;
        g0 = gp[0]; g1 = gp[HID]; g2 = gp[2*HID];
      }
      const float wvv = pollw(tW + c*512 + tid, tg);
      wl[tid] = wvv;
      __syncthreads();
      if (wv < 4) {
        const float4 w0 = WL4[lane], w1 = WL4[64 + lane];
        float sw = w0.x+w0.y+w0.z+w0.w + w1.x+w1.y+w1.z+w1.w;
        sw = wred64(sw);
        const float inv = 1.f / sw;
        const float d0 = wred64(qdot2(wreg[36], wreg[37], w0, w1));
        const float d1 = wred64(qdot2(wreg[38], wreg[39], w0, w1));
        const float d2 = wred64(qdot2(wreg[40], wreg[41], w0, w1));
        const float rg = fast_sigmoid(d0*inv + g0 + gh0r);
        const float zg = fast_sigmoid(d1*inv + g1 + gh0z);
        const float ng = fast_tanh(d2*inv + g2 + rg * gh0n);
        const float h0j = xva[j];                      // h0n[j], read precedes publish
        const float nv = (1.f - zg) * ng + zg * h0j;
        if (lane == 0) stq(tNH0 + c*1024 + j, nv, tg);
      }
    }

    // ===== S3: gather nh0 -> xva; nh1 gates; e0/u0 partials; publish nh1 =====
    {
      float x0, x1;
      poll2e(tNH0 + c*1024 + tid, tNH0 + c*1024 + 512 + tid, tg, x0, x1);
      xva[tid] = x0; xva[tid + 512] = x1;
      __syncthreads();
      const float4 y0 = XA4[lane], y1 = XA4[64+lane], y2 = XA4[128+lane], y3 = XA4[192+lane];
      if (wv < 4) {
        const float a0 = wred64(qdot4(wreg[12], wreg[13], wreg[14], wreg[15], y0,y1,y2,y3));
        const float a1 = wred64(qdot4(wreg[16], wreg[17], wreg[18], wreg[19], y0,y1,y2,y3));
        const float a2 = wred64(qdot4(wreg[20], wreg[21], wreg[22], wreg[23], y0,y1,y2,y3));
        const float rg = fast_sigmoid(a0 + c1r + gh1r);
        const float zg = fast_sigmoid(a1 + c1z + gh1z);
        const float ng = fast_tanh(a2 + c1n + rg * gh1n);
        const float nv = (1.f - zg) * ng + zg * oldn;
        oldn = nv;
        if (lane == 0) {
          stq(tNH1 + c*1024 + j, nv, tg);
          H1[(size_t)t * HID + j] = nv;
        }
      } else if (wv >= 6) {
        float acc = wred64(qdot4(wreg[0], wreg[1], wreg[2], wreg[3], y0,y1,y2,y3));
        if (lane == 0) {
          if (wv == 6) stq(tE0 + c*256 + wg, vhW * fast_tanh(acc + bhW), tg);
          else         stq(tU0 + c*256 + wg, acc, tg);
        }
      }
    }

    // ===== S4: gather nh1 -> xvb; gh1_next (regs); e1/u1 partials =====
    {
      float x0, x1;
      poll2e(tNH1 + c*1024 + tid, tNH1 + c*1024 + 512 + tid, tg, x0, x1);
      xvb[tid] = x0; xvb[tid + 512] = x1;
      __syncthreads();
      const float4 y0 = XB4[lane], y1 = XB4[64+lane], y2 = XB4[128+lane], y3 = XB4[192+lane];
      if (wv < 4) {
        gh1r = wred64(qdot4(wreg[24], wreg[25], wreg[26], wreg[27], y0,y1,y2,y3)) + bh1r;
        gh1z = wred64(qdot4(wreg[28], wreg[29], wreg[30], wreg[31], y0,y1,y2,y3)) + bh1z;
        gh1n = wred64(qdot4(wreg[32], wreg[33], wreg[34], wreg[35], y0,y1,y2,y3)) + bh1n;
      } else if (wv >= 6) {
        float acc = wred64(qdot4(wreg[0], wreg[1], wreg[2], wreg[3], y0,y1,y2,y3));
        if (lane == 0) {
          if (wv == 6) stq(tE1 + c*256 + wg, vhW * fast_tanh(acc + bhW), tg);
          else         stq(tU1 + c*256 + wg, acc, tg);
        }
      }
    }
  }
}

// ---------------- output head: logits -> exp -> per-wave row partials ----------------
__global__ __launch_bounds__(256) void k_head(
    const float* __restrict__ FC1, const float* __restrict__ Wf2,
    const float* __restrict__ bf2, float* __restrict__ out, float* __restrict__ rowp)
{
  __shared__ float fcb[256 * 32];
  const int v = blockIdx.x * 256 + threadIdx.x;
  const bool ok = v < VOC;
  float wf[32];
  float bb = 0.f;
  if (ok) {
    const float4* W4 = (const float4*)(Wf2 + (size_t)v * 32);
    #pragma unroll
    for (int q = 0; q < 8; ++q) ((float4*)wf)[q] = W4[q];
    bb = bf2[v];
  }
  const int wv = threadIdx.x >> 6;
  #pragma unroll 1
  for (int half = 0; half < 2; ++half) {
    __syncthreads();
    for (int i = threadIdx.x; i < 256 * 32 / 4; i += 256)
      ((float4*)fcb)[i] = ((const float4*)(FC1 + half * 256 * 32))[i];
    __syncthreads();
    #pragma unroll 1
    for (int tt = 0; tt < 256; ++tt) {
      const int t = half * 256 + tt;
      const float4* f4 = (const float4*)(fcb + tt * 32);
      float acc = bb;
      #pragma unroll
      for (int q = 0; q < 8; ++q) {
        float4 f = f4[q];
        acc = fmaf(wf[4*q+0], f.x, acc);
        acc = fmaf(wf[4*q+1], f.y, acc);
        acc = fmaf(wf[4*q+2], f.z, acc);
        acc = fmaf(wf[4*q+3], f.w, acc);
      }
      const float w = ok ? __expf(acc) : 0.f;
      if (ok) out[(size_t)t * VOC + v] = w;
      float r = wred64(w);
      if ((threadIdx.x & 63) == 0)
        rowp[(size_t)t * NPART + (size_t)blockIdx.x * 4 + wv] = r;
    }
  }
}

__global__ __launch_bounds__(256) void k_rowsum(const float* __restrict__ rowp, float* __restrict__ inv) {
  const int t = blockIdx.x;
  float acc = 0.f;
  for (int i = threadIdx.x; i < NPART; i += 256) acc += rowp[(size_t)t * NPART + i];
  acc = wred64(acc);
  __shared__ float sr[4];
  if ((threadIdx.x & 63) == 0) sr[threadIdx.x >> 6] = acc;
  __syncthreads();
  if (threadIdx.x == 0) inv[t] = 1.f / (sr[0] + sr[1] + sr[2] + sr[3]);
}

__global__ __launch_bounds__(256) void k_scale(float* __restrict__ out, const float* __restrict__ inv) {
  const int t = blockIdx.y;
  const float s = inv[t];
  const size_t base = (size_t)t * VOC;
  const int v0 = blockIdx.x * 2048 + threadIdx.x;
  #pragma unroll
  for (int k = 0; k < 8; ++k) {
    const int v = v0 + k * 256;
    if (v < VOC) out[base + v] *= s;
  }
}

extern "C" void kernel_launch(void* const* d_in, const int* in_sizes, int n_in,
                              void* d_out, int out_size, void* d_ws, size_t ws_size,
                              hipStream_t stream) {
  const int*   dec  = (const int*)  d_in[0];
  const float* enc  = (const float*)d_in[1];
  const float* emb  = (const float*)d_in[2];
  const float* Wax  = (const float*)d_in[3];
  const float* Wac  = (const float*)d_in[4];
  const float* ba   = (const float*)d_in[5];
  const float* va   = (const float*)d_in[6];
  const float* vab  = (const float*)d_in[7];
  const float* Wih0 = (const float*)d_in[8];
  const float* bih0 = (const float*)d_in[9];
  const float* Whh0 = (const float*)d_in[10];
  const float* bhh0 = (const float*)d_in[11];
  const float* Wih1 = (const float*)d_in[12];
  const float* bih1 = (const float*)d_in[13];
  const float* Whh1 = (const float*)d_in[14];
  const float* bhh1 = (const float*)d_in[15];
  const float* Wh   = (const float*)d_in[16];
  const float* bh   = (const float*)d_in[17];
  const float* vh   = (const float*)d_in[18];
  const float* vhb  = (const float*)d_in[19];
  const float* Wf1  = (const float*)d_in[20];
  const float* bf1  = (const float*)d_in[21];
  const float* Wf2  = (const float*)d_in[22];
  const float* bf2  = (const float*)d_in[23];
  float* out = (float*)d_out;
  float* ws  = (float*)d_ws;

  k_init<<<28, 256, 0, stream>>>(ws);   // 28*256 == TG_TOT

  // Genc[r][s] = Wih0[r, :1024] . enc[s]          (M=3072, N=512)
  k_gemm<<<dim3(8, 48), 256, 0, stream>>>(Wih0, 2048, nullptr, enc, 1024, 0,
                                          nullptr, ws + WS_GENC, 512, G3, S_LEN, 0);
  // gi_tok[t][r] = emb[dec[t]] . Wih0[r, 1024:] + bih0[r]   (M=512, N=3072)
  k_gemm<<<dim3(48, 8), 256, 0, stream>>>(emb, 1024, dec, Wih0, 2048, 1024,
                                          bih0, ws + WS_GITOK, G3, T_LEN, G3, 0);
  // Ex[s][i] = enc[s] . Wa_x[i] + ba[i]           (M=512, N=256)
  k_gemm<<<dim3(4, 8), 256, 0, stream>>>(enc, 1024, nullptr, Wax, 1024, 0,
                                         ba, ws + WS_EX, AD, S_LEN, AD, 0);

  k_recur<<<NWG, NT, 0, stream>>>(ws, Whh0, bhh0, Wih1, bih1, Whh1, bhh1,
                                  Wh, bh, vh, vhb, va, vab, Wac);

  // FC1[t] = relu(Wf1 @ H1[t] + bf1)              (M=512, N=32)
  k_gemm<<<dim3(1, 8), 256, 0, stream>>>(ws + WS_H1, 1024, nullptr, Wf1, 1024, 0,
                                         bf1, ws + WS_FC1, 32, T_LEN, 32, 1);

  k_head<<<197, 256, 0, stream>>>(ws + WS_FC1, Wf2, bf2, out, ws + WS_ROWP);
  k_rowsum<<<512, 256, 0, stream>>>(ws + WS_ROWP, ws + WS_INV);
  k_scale<<<dim3(25, 512), 256, 0, stream>>>(out, ws + WS_INV);
}

// Round 6
// 7123.898 us; speedup vs baseline: 1.1588x; 1.1588x over previous
//
#include <hip/hip_runtime.h>
#include <cstdint>
#include <cstddef>

#define T_LEN 512
#define S_LEN 512
#define HID   1024
#define AD    256
#define VOC   50257
#define G3    3072
#define NWG   256
#define NT    512
#define NPART (197*4)

typedef unsigned long long u64;

// ---------------- workspace layout (float offsets) ----------------
#define WS_GENC   0
#define WS_GITOK  (WS_GENC + G3*S_LEN)
#define WS_EX     (WS_GITOK + T_LEN*G3)
#define WS_H1     (WS_EX + S_LEN*AD)
#define WS_FC1    (WS_H1 + T_LEN*HID)
#define WS_ROWP   (WS_FC1 + T_LEN*32)
#define WS_INV    (WS_ROWP + T_LEN*NPART)
#define WS_TAGF   (((WS_INV + T_LEN) + 15) & ~15)   // 64B-aligned

// ---- tagged-dataflow region: one 64B line (8 u64) per producer WG ----
// LNH0[c][p][0..3]=nh0 cols, LNH1 same, LW[c][p][0..1]=w rows, LEU[c][p]={e0,u0,e1,u1}
#define TG_NH0 0
#define TG_NH1 (TG_NH0 + 2*256*8)
#define TG_W   (TG_NH1 + 2*256*8)
#define TG_EU  (TG_W   + 2*256*8)
#define TG_TOT (TG_EU  + 2*256*8)                    // 16384 u64 = 128KB

__device__ inline float wred64(float v) {
  v += __shfl_xor(v, 32, 64); v += __shfl_xor(v, 16, 64); v += __shfl_xor(v, 8, 64);
  v += __shfl_xor(v, 4, 64);  v += __shfl_xor(v, 2, 64);  v += __shfl_xor(v, 1, 64);
  return v;
}
__device__ inline float fast_sigmoid(float x) { return 1.f / (1.f + __expf(-x)); }
__device__ inline float fast_tanh(float x) {
  float e = __expf(2.f * x);
  return 1.f - 2.f / (e + 1.f);
}

__device__ inline u64 ald(const u64* p) {
  return __hip_atomic_load(p, __ATOMIC_RELAXED, __HIP_MEMORY_SCOPE_AGENT);
}
__device__ inline void stq(u64* p, float v, unsigned tag) {
  __hip_atomic_store(p, ((u64)tag << 32) | (u64)__float_as_uint(v),
                     __ATOMIC_RELAXED, __HIP_MEMORY_SCOPE_AGENT);
}
#define LO_F(x) __uint_as_float((unsigned)(x))

// batched one-line polls (unconditional reload of the whole set each round)
__device__ inline void poll_line4(const u64* L, unsigned tag,
                                  float& r0, float& r1, float& r2, float& r3) {
  u64 x0, x1, x2, x3;
  for (;;) {
    x0 = ald(L); x1 = ald(L + 1); x2 = ald(L + 2); x3 = ald(L + 3);
    if ((((unsigned)(x0 >> 32)) == tag) & (((unsigned)(x1 >> 32)) == tag) &
        (((unsigned)(x2 >> 32)) == tag) & (((unsigned)(x3 >> 32)) == tag)) break;
    __builtin_amdgcn_s_sleep(4);
  }
  r0 = LO_F(x0); r1 = LO_F(x1); r2 = LO_F(x2); r3 = LO_F(x3);
}
__device__ inline void poll_line2(const u64* L, unsigned tag, float& r0, float& r1) {
  u64 x0, x1;
  for (;;) {
    x0 = ald(L); x1 = ald(L + 1);
    if ((((unsigned)(x0 >> 32)) == tag) & (((unsigned)(x1 >> 32)) == tag)) break;
    __builtin_amdgcn_s_sleep(4);
  }
  r0 = LO_F(x0); r1 = LO_F(x1);
}

__device__ inline float qdot4(const float4& a0, const float4& a1, const float4& a2, const float4& a3,
                              const float4& x0, const float4& x1, const float4& x2, const float4& x3) {
  float a = 0.f;
  a = fmaf(a0.x, x0.x, a); a = fmaf(a0.y, x0.y, a); a = fmaf(a0.z, x0.z, a); a = fmaf(a0.w, x0.w, a);
  a = fmaf(a1.x, x1.x, a); a = fmaf(a1.y, x1.y, a); a = fmaf(a1.z, x1.z, a); a = fmaf(a1.w, x1.w, a);
  a = fmaf(a2.x, x2.x, a); a = fmaf(a2.y, x2.y, a); a = fmaf(a2.z, x2.z, a); a = fmaf(a2.w, x2.w, a);
  a = fmaf(a3.x, x3.x, a); a = fmaf(a3.y, x3.y, a); a = fmaf(a3.z, x3.z, a); a = fmaf(a3.w, x3.w, a);
  return a;
}
__device__ inline float qdot2(const float4& a0, const float4& a1,
                              const float4& x0, const float4& x1) {
  float a = 0.f;
  a = fmaf(a0.x, x0.x, a); a = fmaf(a0.y, x0.y, a); a = fmaf(a0.z, x0.z, a); a = fmaf(a0.w, x0.w, a);
  a = fmaf(a1.x, x1.x, a); a = fmaf(a1.y, x1.y, a); a = fmaf(a1.z, x1.z, a); a = fmaf(a1.w, x1.w, a);
  return a;
}

// ---------------- init: zero all tag words ----------------
__global__ void k_init(float* ws) {
  u64* TG = (u64*)(ws + WS_TAGF);
  const int i = blockIdx.x * 256 + threadIdx.x;
  if (i < TG_TOT) TG[i] = 0ull;
}

// ---------------- generic tiled fp32 GEMM (pre/post passes) ----------------
__global__ __launch_bounds__(256) void k_gemm(
    const float* __restrict__ A, int lda, const int* __restrict__ gidx,
    const float* __restrict__ B, int ldb, int kofs,
    const float* __restrict__ bias, float* __restrict__ C, int ldc,
    int M, int N, int act)
{
  __shared__ float As[64][33];
  __shared__ float Bs[64][33];
  const int bm = blockIdx.y * 64, bn = blockIdx.x * 64;
  const int tx = threadIdx.x & 15, ty = threadIdx.x >> 4;
  float acc[4][4] = {};
  const int lin = threadIdx.x * 8;
  const int lr = lin >> 5;
  const int lc = lin & 31;
  for (int k0 = 0; k0 < 1024; k0 += 32) {
    {
      const int gm = bm + lr;
      float4 v0 = {0,0,0,0}, v1 = {0,0,0,0};
      if (gm < M) {
        const int row = gidx ? gidx[gm] : gm;
        const float* p = A + (size_t)row * lda + k0 + lc;
        v0 = *(const float4*)p; v1 = *(const float4*)(p + 4);
      }
      As[lr][lc+0]=v0.x; As[lr][lc+1]=v0.y; As[lr][lc+2]=v0.z; As[lr][lc+3]=v0.w;
      As[lr][lc+4]=v1.x; As[lr][lc+5]=v1.y; As[lr][lc+6]=v1.z; As[lr][lc+7]=v1.w;
    }
    {
      const int gn = bn + lr;
      float4 v0 = {0,0,0,0}, v1 = {0,0,0,0};
      if (gn < N) {
        const float* p = B + (size_t)gn * ldb + kofs + k0 + lc;
        v0 = *(const float4*)p; v1 = *(const float4*)(p + 4);
      }
      Bs[lr][lc+0]=v0.x; Bs[lr][lc+1]=v0.y; Bs[lr][lc+2]=v0.z; Bs[lr][lc+3]=v0.w;
      Bs[lr][lc+4]=v1.x; Bs[lr][lc+5]=v1.y; Bs[lr][lc+6]=v1.z; Bs[lr][lc+7]=v1.w;
    }
    __syncthreads();
    #pragma unroll
    for (int kk = 0; kk < 32; ++kk) {
      float a0 = As[ty*4+0][kk], a1 = As[ty*4+1][kk], a2 = As[ty*4+2][kk], a3 = As[ty*4+3][kk];
      float b0 = Bs[tx*4+0][kk], b1 = Bs[tx*4+1][kk], b2 = Bs[tx*4+2][kk], b3 = Bs[tx*4+3][kk];
      acc[0][0]=fmaf(a0,b0,acc[0][0]); acc[0][1]=fmaf(a0,b1,acc[0][1]); acc[0][2]=fmaf(a0,b2,acc[0][2]); acc[0][3]=fmaf(a0,b3,acc[0][3]);
      acc[1][0]=fmaf(a1,b0,acc[1][0]); acc[1][1]=fmaf(a1,b1,acc[1][1]); acc[1][2]=fmaf(a1,b2,acc[1][2]); acc[1][3]=fmaf(a1,b3,acc[1][3]);
      acc[2][0]=fmaf(a2,b0,acc[2][0]); acc[2][1]=fmaf(a2,b1,acc[2][1]); acc[2][2]=fmaf(a2,b2,acc[2][2]); acc[2][3]=fmaf(a2,b3,acc[2][3]);
      acc[3][0]=fmaf(a3,b0,acc[3][0]); acc[3][1]=fmaf(a3,b1,acc[3][1]); acc[3][2]=fmaf(a3,b2,acc[3][2]); acc[3][3]=fmaf(a3,b3,acc[3][3]);
    }
    __syncthreads();
  }
  #pragma unroll
  for (int i = 0; i < 4; ++i)
    #pragma unroll
    for (int j = 0; j < 4; ++j) {
      const int m = bm + ty*4 + i, n = bn + tx*4 + j;
      if (m < M && n < N) {
        float v = acc[i][j] + (bias ? bias[n] : 0.f);
        if (act == 1) v = fmaxf(v, 0.f);
        C[(size_t)m * ldc + n] = v;
      }
    }
}

// ---------------- persistent recurrence: 256 WGs x 512 thr ----------------
// LDS-resident weights: lW[3 mats][12 gate-rows][1024] (144KB, loaded once).
// Wave wv<4 owns column j=4wg+wv (rows part*4+wv of each LDS matrix block + Genc regs).
// Waves 4,5: attention-w rows 2wg+(wv-4). Wave 6: Wh row wg. Wave 7: Wac row wg.
__global__ __launch_bounds__(NT) void k_recur(
    float* __restrict__ ws,
    const float* __restrict__ Whh0, const float* __restrict__ bhh0,
    const float* __restrict__ Wih1, const float* __restrict__ bih1,
    const float* __restrict__ Whh1, const float* __restrict__ bhh1,
    const float* __restrict__ Wh,   const float* __restrict__ bh,
    const float* __restrict__ vh,   const float* __restrict__ vhb,
    const float* __restrict__ va,   const float* __restrict__ vab,
    const float* __restrict__ Wac)
{
  const float* Genc  = ws + WS_GENC;
  const float* gitok = ws + WS_GITOK;
  const float* Ex    = ws + WS_EX;
  float* H1 = ws + WS_H1;
  u64* TG   = (u64*)(ws + WS_TAGF);
  u64* tNH0 = TG + TG_NH0;
  u64* tNH1 = TG + TG_NH1;
  u64* tW   = TG + TG_W;
  u64* tEU  = TG + TG_EU;

  const int wg = blockIdx.x, tid = threadIdx.x;
  const int lane = tid & 63, wv = tid >> 6;
  const int j = wg * 4 + (wv & 3);

  __shared__ float lW[36 * 1024];     // 144KB weights
  __shared__ float xva[HID];          // nh0 / h0n staging
  __shared__ float xvb[HID];          // nh1 staging
  __shared__ float wl[S_LEN];
  __shared__ float cb[AD];
  __shared__ float sred[8];

  // ---- one-time: weights -> LDS ----
  #pragma unroll 1
  for (int idx = tid; idx < 36 * 256; idx += NT) {
    const int row = idx >> 8, c4 = idx & 255;
    const int m = row / 12, rr = row - m * 12;
    const int part = rr >> 2, jl = rr & 3;
    const float* src = (m == 0 ? Whh0 : (m == 1 ? Wih1 : Whh1))
                       + (size_t)(part * HID + wg * 4 + jl) * HID;
    ((float4*)lW)[row * 256 + c4] = ((const float4*)src)[c4];
  }

  // ---- small register-resident weights ----
  float4 greg[6];                     // Genc rows (wv<4)
  float4 exr = {0,0,0,0}, var = {0,0,0,0};
  float4 whr[4] = {{0,0,0,0},{0,0,0,0},{0,0,0,0},{0,0,0,0}};
  if (wv < 4) {
    #pragma unroll
    for (int part = 0; part < 3; ++part) {
      const float4* pg = (const float4*)(Genc + (size_t)(part * HID + j) * S_LEN);
      greg[part * 2]     = pg[lane];
      greg[part * 2 + 1] = pg[64 + lane];
    }
  } else if (wv < 6) {
    const int s = 2 * wg + (wv - 4);
    exr = ((const float4*)(Ex + (size_t)s * AD))[lane];
    var = ((const float4*)va)[lane];
  } else {
    const float* Wrow = (wv == 6) ? (Wh + (size_t)wg * HID) : (Wac + (size_t)wg * HID);
    #pragma unroll
    for (int p = 0; p < 4; ++p) whr[p] = ((const float4*)Wrow)[p * 64 + lane];
  }

  float b0r=0,b0z=0,b0n=0, c1r=0,c1z=0,c1n=0, bh1r=0,bh1z=0,bh1n=0;
  float gh1r=0, gh1z=0, gh1n=0, oldn=0.f;
  if (wv < 4) {
    b0r = bhh0[j];  b0z = bhh0[HID+j];  b0n = bhh0[2*HID+j];
    c1r = bih1[j];  c1z = bih1[HID+j];  c1n = bih1[2*HID+j];
    bh1r = bhh1[j]; bh1z = bhh1[HID+j]; bh1n = bhh1[2*HID+j];
    gh1r = bh1r; gh1z = bh1z; gh1n = bh1n;     // gh1(t=0) = Whh1@0 + bhh1
  }
  const float vhW = vh[wg], bhW = bh[wg];
  const float vabv = vab[0], vhb0 = vhb[0];

  xva[tid] = 0.f; xva[tid + 512] = 0.f;
  xvb[tid] = 0.f; xvb[tid + 512] = 0.f;
  __syncthreads();

  const float4* XA4 = (const float4*)xva;
  const float4* XB4 = (const float4*)xvb;
  const float4* WL4 = (const float4*)wl;
  const float4* R4  = (const float4*)lW;
  float gh0r = 0.f, gh0z = 0.f, gh0n = 0.f;

  #pragma unroll 1
  for (int t = 0; t < T_LEN; ++t) {
    const int c = t & 1, pc = c ^ 1;
    const unsigned tg = (unsigned)(t + 1);
    const unsigned tp = (unsigned)t;

    // ===== S1: gather e/u; alpha; h0n (in-place xva); c; gh0 (regs); publish w =====
    {
      float e0c = 0.f, u0v = 0.f, e1c = 0.f, u1v = 0.f;
      if (tid < 256)
        poll_line4(tEU + ((size_t)pc * 256 + tid) * 8, tp, e0c, u0v, e1c, u1v);
      float r0 = wred64(e0c), r1 = wred64(e1c);
      if (wv < 4 && lane == 0) { sred[wv] = r0; sred[4 + wv] = r1; }
      __syncthreads();
      const float e0s = sred[0] + sred[1] + sred[2] + sred[3] + vhb0;
      const float e1s = sred[4] + sred[5] + sred[6] + sred[7] + vhb0;
      const float ea = __expf(e0s), eb = __expf(e1s);
      const float rs = 1.f / (ea + eb);
      const float al0 = ea * rs, al1 = eb * rs;
      const float h0 = al0 * xva[tid]       + al1 * xvb[tid];
      const float h1 = al0 * xva[tid + 512] + al1 * xvb[tid + 512];
      xva[tid] = h0; xva[tid + 512] = h1;
      if (tid < 256) cb[tid] = al0 * u0v + al1 * u1v;
      __syncthreads();
      if (wv < 4) {
        const float4 x0 = XA4[lane], x1 = XA4[64+lane], x2 = XA4[128+lane], x3 = XA4[192+lane];
        const int b0 = (0 + wv) * 256, b1 = (4 + wv) * 256, b2 = (8 + wv) * 256;
        gh0r = wred64(qdot4(R4[b0+lane], R4[b0+64+lane], R4[b0+128+lane], R4[b0+192+lane], x0,x1,x2,x3)) + b0r;
        gh0z = wred64(qdot4(R4[b1+lane], R4[b1+64+lane], R4[b1+128+lane], R4[b1+192+lane], x0,x1,x2,x3)) + b0z;
        gh0n = wred64(qdot4(R4[b2+lane], R4[b2+64+lane], R4[b2+128+lane], R4[b2+192+lane], x0,x1,x2,x3)) + b0n;
      } else if (wv < 6) {
        const float4 c4 = ((const float4*)cb)[lane];
        float acc = var.x * fast_tanh(exr.x + c4.x) + var.y * fast_tanh(exr.y + c4.y)
                  + var.z * fast_tanh(exr.z + c4.z) + var.w * fast_tanh(exr.w + c4.w);
        acc = wred64(acc);
        if (lane == 0)
          stq(tW + ((size_t)c * 256 + wg) * 8 + (wv - 4), __expf(acc + vabv), tg);
      }
    }

    // ===== S2: gather w; nh0 = GRU0((Genc@w)/sum + gitok, gh0, h0n); publish nh0 =====
    {
      float g0 = 0.f, g1 = 0.f, g2 = 0.f;
      if (wv < 4) {
        const float* gp = gitok + (size_t)t * G3 + j;
        g0 = gp[0]; g1 = gp[HID]; g2 = gp[2 * HID];
      }
      if (tid < 256) {
        float w0v, w1v;
        poll_line2(tW + ((size_t)c * 256 + tid) * 8, tg, w0v, w1v);
        wl[2 * tid] = w0v; wl[2 * tid + 1] = w1v;
      }
      __syncthreads();
      if (wv < 4) {
        const float4 w0 = WL4[lane], w1 = WL4[64 + lane];
        float sw = w0.x+w0.y+w0.z+w0.w + w1.x+w1.y+w1.z+w1.w;
        float a0 = qdot2(greg[0], greg[1], w0, w1);
        float a1 = qdot2(greg[2], greg[3], w0, w1);
        float a2 = qdot2(greg[4], greg[5], w0, w1);
        sw = wred64(sw); a0 = wred64(a0); a1 = wred64(a1); a2 = wred64(a2);
        const float inv = 1.f / sw;
        const float rg = fast_sigmoid(a0 * inv + g0 + gh0r);
        const float zg = fast_sigmoid(a1 * inv + g1 + gh0z);
        const float ng = fast_tanh(a2 * inv + g2 + rg * gh0n);
        const float h0j = xva[j];
        const float nv = (1.f - zg) * ng + zg * h0j;
        if (lane == 0) stq(tNH0 + ((size_t)c * 256 + wg) * 8 + wv, nv, tg);
      }
    }

    // ===== S3: gather nh0 -> xva; nh1 gates; e0/u0; publish nh1 =====
    __syncthreads();   // protect xva rewrite vs lagging S2 readers
    {
      if (tid < 256) {
        float v0, v1, v2, v3;
        poll_line4(tNH0 + ((size_t)c * 256 + tid) * 8, tg, v0, v1, v2, v3);
        float4 v; v.x = v0; v.y = v1; v.z = v2; v.w = v3;
        ((float4*)xva)[tid] = v;
      }
      __syncthreads();
      const float4 y0 = XA4[lane], y1 = XA4[64+lane], y2 = XA4[128+lane], y3 = XA4[192+lane];
      if (wv < 4) {
        const int b0 = (12 + wv) * 256, b1 = (16 + wv) * 256, b2 = (20 + wv) * 256;
        float a0 = wred64(qdot4(R4[b0+lane], R4[b0+64+lane], R4[b0+128+lane], R4[b0+192+lane], y0,y1,y2,y3));
        float a1 = wred64(qdot4(R4[b1+lane], R4[b1+64+lane], R4[b1+128+lane], R4[b1+192+lane], y0,y1,y2,y3));
        float a2 = wred64(qdot4(R4[b2+lane], R4[b2+64+lane], R4[b2+128+lane], R4[b2+192+lane], y0,y1,y2,y3));
        const float rg = fast_sigmoid(a0 + c1r + gh1r);
        const float zg = fast_sigmoid(a1 + c1z + gh1z);
        const float ng = fast_tanh(a2 + c1n + rg * gh1n);
        const float nv = (1.f - zg) * ng + zg * oldn;
        oldn = nv;
        if (lane == 0) {
          stq(tNH1 + ((size_t)c * 256 + wg) * 8 + wv, nv, tg);
          H1[(size_t)t * HID + j] = nv;
        }
      } else if (wv >= 6) {
        float acc = wred64(qdot4(whr[0], whr[1], whr[2], whr[3], y0, y1, y2, y3));
        if (lane == 0) {
          if (wv == 6) stq(tEU + ((size_t)c * 256 + wg) * 8 + 0, vhW * fast_tanh(acc + bhW), tg);
          else         stq(tEU + ((size_t)c * 256 + wg) * 8 + 1, acc, tg);
        }
      }
    }

    // ===== S4: gather nh1 -> xvb; gh1_next (regs); e1/u1 =====
    {
      if (tid < 256) {
        float v0, v1, v2, v3;
        poll_line4(tNH1 + ((size_t)c * 256 + tid) * 8, tg, v0, v1, v2, v3);
        float4 v; v.x = v0; v.y = v1; v.z = v2; v.w = v3;
        ((float4*)xvb)[tid] = v;
      }
      __syncthreads();
      const float4 y0 = XB4[lane], y1 = XB4[64+lane], y2 = XB4[128+lane], y3 = XB4[192+lane];
      if (wv < 4) {
        const int b0 = (24 + wv) * 256, b1 = (28 + wv) * 256, b2 = (32 + wv) * 256;
        gh1r = wred64(qdot4(R4[b0+lane], R4[b0+64+lane], R4[b0+128+lane], R4[b0+192+lane], y0,y1,y2,y3)) + bh1r;
        gh1z = wred64(qdot4(R4[b1+lane], R4[b1+64+lane], R4[b1+128+lane], R4[b1+192+lane], y0,y1,y2,y3)) + bh1z;
        gh1n = wred64(qdot4(R4[b2+lane], R4[b2+64+lane], R4[b2+128+lane], R4[b2+192+lane], y0,y1,y2,y3)) + bh1n;
      } else if (wv >= 6) {
        float acc = wred64(qdot4(whr[0], whr[1], whr[2], whr[3], y0, y1, y2, y3));
        if (lane == 0) {
          if (wv == 6) stq(tEU + ((size_t)c * 256 + wg) * 8 + 2, vhW * fast_tanh(acc + bhW), tg);
          else         stq(tEU + ((size_t)c * 256 + wg) * 8 + 3, acc, tg);
        }
      }
    }
  }
}

// ---------------- output head ----------------
__global__ __launch_bounds__(256) void k_head(
    const float* __restrict__ FC1, const float* __restrict__ Wf2,
    const float* __restrict__ bf2, float* __restrict__ out, float* __restrict__ rowp)
{
  __shared__ float fcb[256 * 32];
  const int v = blockIdx.x * 256 + threadIdx.x;
  const bool ok = v < VOC;
  float wf[32];
  float bb = 0.f;
  if (ok) {
    const float4* W4 = (const float4*)(Wf2 + (size_t)v * 32);
    #pragma unroll
    for (int q = 0; q < 8; ++q) ((float4*)wf)[q] = W4[q];
    bb = bf2[v];
  }
  const int wv = threadIdx.x >> 6;
  #pragma unroll 1
  for (int half = 0; half < 2; ++half) {
    __syncthreads();
    for (int i = threadIdx.x; i < 256 * 32 / 4; i += 256)
      ((float4*)fcb)[i] = ((const float4*)(FC1 + half * 256 * 32))[i];
    __syncthreads();
    #pragma unroll 1
    for (int tt = 0; tt < 256; ++tt) {
      const int t = half * 256 + tt;
      const float4* f4 = (const float4*)(fcb + tt * 32);
      float acc = bb;
      #pragma unroll
      for (int q = 0; q < 8; ++q) {
        float4 f = f4[q];
        acc = fmaf(wf[4*q+0], f.x, acc);
        acc = fmaf(wf[4*q+1], f.y, acc);
        acc = fmaf(wf[4*q+2], f.z, acc);
        acc = fmaf(wf[4*q+3], f.w, acc);
      }
      const float w = ok ? __expf(acc) : 0.f;
      if (ok) out[(size_t)t * VOC + v] = w;
      float r = wred64(w);
      if ((threadIdx.x & 63) == 0)
        rowp[(size_t)t * NPART + (size_t)blockIdx.x * 4 + wv] = r;
    }
  }
}

__global__ __launch_bounds__(256) void k_rowsum(const float* __restrict__ rowp, float* __restrict__ inv) {
  const int t = blockIdx.x;
  float acc = 0.f;
  for (int i = threadIdx.x; i < NPART; i += 256) acc += rowp[(size_t)t * NPART + i];
  acc = wred64(acc);
  __shared__ float sr[4];
  if ((threadIdx.x & 63) == 0) sr[threadIdx.x >> 6] = acc;
  __syncthreads();
  if (threadIdx.x == 0) inv[t] = 1.f / (sr[0] + sr[1] + sr[2] + sr[3]);
}

__global__ __launch_bounds__(256) void k_scale(float* __restrict__ out, const float* __restrict__ inv) {
  const int t = blockIdx.y;
  const float s = inv[t];
  const size_t base = (size_t)t * VOC;
  const int v0 = blockIdx.x * 2048 + threadIdx.x;
  #pragma unroll
  for (int k = 0; k < 8; ++k) {
    const int v = v0 + k * 256;
    if (v < VOC) out[base + v] *= s;
  }
}

extern "C" void kernel_launch(void* const* d_in, const int* in_sizes, int n_in,
                              void* d_out, int out_size, void* d_ws, size_t ws_size,
                              hipStream_t stream) {
  const int*   dec  = (const int*)  d_in[0];
  const float* enc  = (const float*)d_in[1];
  const float* emb  = (const float*)d_in[2];
  const float* Wax  = (const float*)d_in[3];
  const float* Wac  = (const float*)d_in[4];
  const float* ba   = (const float*)d_in[5];
  const float* va   = (const float*)d_in[6];
  const float* vab  = (const float*)d_in[7];
  const float* Wih0 = (const float*)d_in[8];
  const float* bih0 = (const float*)d_in[9];
  const float* Whh0 = (const float*)d_in[10];
  const float* bhh0 = (const float*)d_in[11];
  const float* Wih1 = (const float*)d_in[12];
  const float* bih1 = (const float*)d_in[13];
  const float* Whh1 = (const float*)d_in[14];
  const float* bhh1 = (const float*)d_in[15];
  const float* Wh   = (const float*)d_in[16];
  const float* bh   = (const float*)d_in[17];
  const float* vh   = (const float*)d_in[18];
  const float* vhb  = (const float*)d_in[19];
  const float* Wf1  = (const float*)d_in[20];
  const float* bf1  = (const float*)d_in[21];
  const float* Wf2  = (const float*)d_in[22];
  const float* bf2  = (const float*)d_in[23];
  float* out = (float*)d_out;
  float* ws  = (float*)d_ws;

  k_init<<<64, 256, 0, stream>>>(ws);   // 64*256 == TG_TOT

  // Genc[r][s] = Wih0[r, :1024] . enc[s]          (M=3072, N=512)
  k_gemm<<<dim3(8, 48), 256, 0, stream>>>(Wih0, 2048, nullptr, enc, 1024, 0,
                                          nullptr, ws + WS_GENC, 512, G3, S_LEN, 0);
  // gi_tok[t][r] = emb[dec[t]] . Wih0[r, 1024:] + bih0[r]   (M=512, N=3072)
  k_gemm<<<dim3(48, 8), 256, 0, stream>>>(emb, 1024, dec, Wih0, 2048, 1024,
                                          bih0, ws + WS_GITOK, G3, T_LEN, G3, 0);
  // Ex[s][i] = enc[s] . Wa_x[i] + ba[i]           (M=512, N=256)
  k_gemm<<<dim3(4, 8), 256, 0, stream>>>(enc, 1024, nullptr, Wax, 1024, 0,
                                         ba, ws + WS_EX, AD, S_LEN, AD, 0);

  k_recur<<<NWG, NT, 0, stream>>>(ws, Whh0, bhh0, Wih1, bih1, Whh1, bhh1,
                                  Wh, bh, vh, vhb, va, vab, Wac);

  // FC1[t] = relu(Wf1 @ H1[t] + bf1)              (M=512, N=32)
  k_gemm<<<dim3(1, 8), 256, 0, stream>>>(ws + WS_H1, 1024, nullptr, Wf1, 1024, 0,
                                         bf1, ws + WS_FC1, 32, T_LEN, 32, 1);

  k_head<<<197, 256, 0, stream>>>(ws + WS_FC1, Wf2, bf2, out, ws + WS_ROWP);
  k_rowsum<<<512, 256, 0, stream>>>(ws + WS_ROWP, ws + WS_INV);
  k_scale<<<dim3(25, 512), 256, 0, stream>>>(out, ws + WS_INV);
}